// Round 10
// baseline (515.330 us; speedup 1.0000x reference)
//
#include <hip/hip_runtime.h>
#include <hip/hip_bf16.h>

typedef __attribute__((ext_vector_type(8))) short bf16x8;
typedef __attribute__((ext_vector_type(4))) short bf16x4;
typedef __attribute__((ext_vector_type(4))) float f32x4;

#define MFMA32(a,b,c) __builtin_amdgcn_mfma_f32_16x16x32_bf16(a,b,c,0,0,0)

#if __has_builtin(__builtin_amdgcn_mfma_f32_16x16x16bf16_1k)
#define MFMA16(a,b,c) __builtin_amdgcn_mfma_f32_16x16x16bf16_1k(a,b,c,0,0,0)
#else
static __device__ __forceinline__ f32x4 mfma16_asm(bf16x4 a, bf16x4 b, f32x4 c){
  asm volatile("v_mfma_f32_16x16x16_bf16 %0, %1, %2, %0" : "+v"(c) : "v"(a), "v"(b));
  return c;
}
#define MFMA16(a,b,c) mfma16_asm(a,b,c)
#endif

#define NEGV -65504.0f

__device__ __forceinline__ unsigned short f2bf(float f){
  union { float f; unsigned u; } x; x.f = f;
  unsigned r = x.u + 0x7fffu + ((x.u >> 16) & 1u);
  return (unsigned short)(r >> 16);
}

__device__ __forceinline__ unsigned cvtpk(float a, float b){
  unsigned r;
  asm volatile("v_cvt_pk_bf16_f32 %0, %1, %2" : "=v"(r) : "v"(a), "v"(b));
  return r;   // a -> low 16, b -> high 16
}

// ------- fused: fp32->bf16 convert (x, W_qkv, W_proj) + mask int32->bits -------
__global__ __launch_bounds__(256) void cvt_mask(
    const float* __restrict__ x, const float* __restrict__ wq,
    const float* __restrict__ wp, unsigned short* __restrict__ out,
    const int* __restrict__ m, unsigned long long* __restrict__ mb){
  int bid = blockIdx.x;
  if (bid < 8448) {
    int i = bid * 256 + threadIdx.x;
    const float* src; int j;
    if (i < 1572864)      { src = x;  j = i; }
    else if (i < 2015232) { src = wq; j = i - 1572864; }
    else                  { src = wp; j = i - 2015232; }
    float4 f = ((const float4*)src)[j];
    ushort4 u;
    u.x = f2bf(f.x); u.y = f2bf(f.y); u.z = f2bf(f.z); u.w = f2bf(f.w);
    ((ushort4*)out)[i] = u;
  } else {
    int gw = ((bid - 8448) * 256 + threadIdx.x) >> 6;   // wave id 0..8191
    int lane = threadIdx.x & 63;
#pragma unroll
    for (int stp = 0; stp < 16; ++stp) {
      size_t base = ((size_t)gw * 16 + stp) * 64;
      int v = m[base + lane];
      unsigned long long bbm = __ballot(v != 0);
      if (lane == 0) mb[base >> 6] = bbm;
    }
  }
}

// ---------------- LDS-staged QKV GEMM: X[8192,768] @ W[2304,768]^T + b ----------
// contiguous scatter: q(x0.125) -> Qd[bh][n][d], k -> Kd, v -> Vd (R7-proven)
__global__ __launch_bounds__(256) void gemm_qkv(
    const unsigned short* __restrict__ X,
    const unsigned short* __restrict__ W,
    const float* __restrict__ bias,
    unsigned short* __restrict__ Qd,
    unsigned short* __restrict__ Kd,
    unsigned short* __restrict__ Vd)
{
  __shared__ unsigned short As[128*40];
  __shared__ unsigned short Bs[128*40];
  const int K = 768;
  int tid = threadIdx.x;
  int bm = blockIdx.x & 63;
  int bn = blockIdx.x >> 6;
  int wave = tid >> 6, lane = tid & 63;
  int lo = lane & 15, g = lane >> 4;
  int wr = (wave >> 1) * 64, wc = (wave & 1) * 64;
  int row0 = bm * 128, col0 = bn * 128;

  int sr = tid >> 1;
  int sc = (tid & 1) * 16;
  const unsigned short* gA = X + (size_t)(row0 + sr) * K + sc;
  const unsigned short* gB = W + (size_t)(col0 + sr) * K + sc;
  unsigned short* sA = &As[sr * 40 + sc];
  unsigned short* sB = &Bs[sr * 40 + sc];

  f32x4 acc[4][4] = {};
  for (int k0 = 0; k0 < K; k0 += 32) {
    bf16x8 a0 = *(const bf16x8*)(gA + k0);
    bf16x8 a1 = *(const bf16x8*)(gA + k0 + 8);
    bf16x8 b0 = *(const bf16x8*)(gB + k0);
    bf16x8 b1 = *(const bf16x8*)(gB + k0 + 8);
    __syncthreads();
    *(bf16x8*)(sA)     = a0;
    *(bf16x8*)(sA + 8) = a1;
    *(bf16x8*)(sB)     = b0;
    *(bf16x8*)(sB + 8) = b1;
    __syncthreads();
    bf16x8 af[4], bf[4];
#pragma unroll
    for (int i = 0; i < 4; ++i) af[i] = *(const bf16x8*)&As[(wr + i*16 + lo)*40 + g*8];
#pragma unroll
    for (int i = 0; i < 4; ++i) bf[i] = *(const bf16x8*)&Bs[(wc + i*16 + lo)*40 + g*8];
#pragma unroll
    for (int mi = 0; mi < 4; ++mi)
#pragma unroll
      for (int ni = 0; ni < 4; ++ni)
        acc[mi][ni] = MFMA32(af[mi], bf[ni], acc[mi][ni]);
  }
  int orow0 = row0 + wr, ocol0 = col0 + wc;
#pragma unroll
  for (int ni = 0; ni < 4; ++ni) {
    int col = ocol0 + ni*16 + lo;
    float bc = bias[col];
    int which = col / 768;
    int rem = col - which * 768;
    int h = rem >> 6, d = rem & 63;
    unsigned short* dst = (which == 0) ? Qd : (which == 1) ? Kd : Vd;
    float scale = (which == 0) ? 0.125f : 1.0f;
#pragma unroll
    for (int mi = 0; mi < 4; ++mi) {
#pragma unroll
      for (int r = 0; r < 4; ++r) {
        int row = orow0 + mi*16 + g*4 + r;
        int bb = row >> 10, n = row & 1023;
        dst[(((size_t)bb*12 + h)*1024 + n)*64 + d] = f2bf((acc[mi][ni][r] + bc) * scale);
      }
    }
  }
}

// ---------------- V transpose: [96][1024][64] -> [96][64][1024] ----------------
__global__ __launch_bounds__(256) void vtrans(const unsigned short* __restrict__ V,
                                              unsigned short* __restrict__ Vt){
  __shared__ unsigned short t[64][72];
  int bh = blockIdx.y;
  int n0 = blockIdx.x * 64;
  int tid = threadIdx.x;
  int nl = tid >> 2;
  int dq = (tid & 3) * 16;
  const unsigned short* src = V + ((size_t)bh*1024 + n0 + nl)*64 + dq;
  bf16x8 a0 = *(const bf16x8*)(src);
  bf16x8 a1 = *(const bf16x8*)(src + 8);
  *(bf16x8*)&t[nl][dq]     = a0;
  *(bf16x8*)&t[nl][dq + 8] = a1;
  __syncthreads();
  int d  = tid >> 2;
  int nq = (tid & 3) * 16;
  union { unsigned short s[16]; bf16x8 v[2]; } pk;
#pragma unroll
  for (int j = 0; j < 16; ++j) pk.s[j] = t[nq + j][d];
  unsigned short* dst = Vt + ((size_t)bh*64 + d)*1024 + n0 + nq;
  *(bf16x8*)(dst)     = pk.v[0];
  *(bf16x8*)(dst + 8) = pk.v[1];
}

// ---------------- fused attention core, 8 waves x 16 q-rows, LDS-shared K/V ----
// Store-drain fix: bias/mask for it+1 are issued BETWEEN the masked-add and the
// NT stores of it -> consuming them next iter never awaits the stores. Barrier
// waits vmcnt(9) = exactly the 2 stage loads (+ ancient stores).
__global__ __launch_bounds__(512, 8) void attn_kernel(
    const unsigned short* __restrict__ Qd,
    const unsigned short* __restrict__ Kd,
    const unsigned short* __restrict__ Vt,     // [96][64][1024]
    const float* __restrict__ bias,            // [12,1024,1024] fp32
    const unsigned* __restrict__ maskbits,     // [8*1024][32] u32 words
    float* __restrict__ out1,                  // [96,1024,1024] fp32
    unsigned short* __restrict__ ctx)          // [8192,768] bf16
{
  __shared__ char lds[32768];
  const int N = 1024, D = 64;
  int y = blockIdx.y;
  int h = y >> 3, bb = y & 7;
  int bh = bb * 12 + h;
  int tid = threadIdx.x;
  int wave = tid >> 6, lane = tid & 63;
  int lo = lane & 15, g = lane >> 4;
  int qrow = blockIdx.x * 128 + wave * 16 + lo;

  const size_t qoff = ((size_t)bh * N + qrow) * D;
  bf16x8 qf0 = *(const bf16x8*)(Qd + qoff + g*8);
  bf16x8 qf1 = *(const bf16x8*)(Qd + qoff + 32 + g*8);

  const float* bias_row = bias + ((size_t)h * N + qrow) * N;
  const unsigned* mrow  = maskbits + ((size_t)bb * N + qrow) * 32;
  float* out_row        = out1 + ((size_t)bh * N + qrow) * N;

  int o  = tid * 16;
  int sw = o ^ (((o >> 7) & 7) << 4);
  const char* kbase = (const char*)(Kd + (size_t)bh * N * D);
  const char* vbase = (const char*)(Vt + (size_t)bh * D * N);
  const char* ksrc  = kbase + sw;                           // + kv*128 per tile
  const char* vsrc  = vbase + (o >> 7) * 2048 + (sw & 127); // + kv*2 per tile
  int wbase = wave << 10;

#define STAGE(buf, kv) do { \
    __builtin_amdgcn_global_load_lds( \
      (const __attribute__((address_space(1))) unsigned*)(ksrc + (size_t)(kv)*128), \
      (__attribute__((address_space(3))) unsigned*)(lds + (buf)*8192 + wbase), 16, 0, 0); \
    __builtin_amdgcn_global_load_lds( \
      (const __attribute__((address_space(1))) unsigned*)(vsrc + (size_t)(kv)*2), \
      (__attribute__((address_space(3))) unsigned*)(lds + 16384 + (buf)*8192 + wbase), 16, 0, 0); \
  } while (0)

#define SWZ(lb) ((lb) ^ ((((lb) >> 7) & 7) << 4))

  float m_run = -INFINITY, l_part = 0.0f;
  f32x4 oacc[4] = {};

  // prologue: it=0 bias/mask into regs; stage tile 0; full drain
  uint2 mw = *(const uint2*)(mrow);
  f32x4 bi[4];
#pragma unroll
  for (int sub = 0; sub < 4; ++sub)
    bi[sub] = *(const f32x4*)(bias_row + sub*16 + g*4);
  STAGE(0, 0);
  __syncthreads();
  int cur = 0;

  for (int it = 0; it < 16; ++it) {
    int kv = it * 64;
    int kvn = ((it + 1) & 15) << 6;      // clamp: it=15 -> re-stage tile 0 (unused)

    // ---- next-tile stage FIRST (oldest vmem of this iter) ----
    STAGE(cur ^ 1, kvn);
    __builtin_amdgcn_sched_barrier(0);

    // ---- QK^T: s[sub][r] = S[q=lo][kv + sub*16 + g*4 + r] ----
    f32x4 s[4];
    __builtin_amdgcn_s_setprio(1);
#pragma unroll
    for (int sub = 0; sub < 4; ++sub) {
      int lbr = (sub*16 + lo) * 128 + g*16;
      bf16x8 k0 = *(const bf16x8*)(lds + cur*8192 + SWZ(lbr));
      bf16x8 k1 = *(const bf16x8*)(lds + cur*8192 + SWZ(lbr + 64));
      f32x4 t = {};
      t = MFMA32(k0, qf0, t);
      t = MFMA32(k1, qf1, t);
      s[sub] = t;
    }
    __builtin_amdgcn_s_setprio(0);

    // ---- masked-add: consume bi/mw (regs; their loads are older than stage) ----
    float sp[16];
#pragma unroll
    for (int sub = 0; sub < 4; ++sub) {
      unsigned mws = (sub < 2) ? mw.x : mw.y;
      int sh = (sub & 1) * 16 + g * 4;
#pragma unroll
      for (int r = 0; r < 4; ++r)
        sp[sub*4+r] = (((mws >> (sh + r)) & 1u) ? NEGV : s[sub][r]) + bi[sub][r];
    }
    __builtin_amdgcn_sched_barrier(0);

    // ---- issue NEXT bias/mask now: older than the stores below ----
    mw = *(const uint2*)(mrow + (kvn >> 5));
#pragma unroll
    for (int sub = 0; sub < 4; ++sub)
      bi[sub] = *(const f32x4*)(bias_row + kvn + sub*16 + g*4);
    __builtin_amdgcn_sched_barrier(0);

    // ---- out1 dump (NT, newest -> never awaited) ----
#pragma unroll
    for (int sub = 0; sub < 4; ++sub) {
      f32x4 ov;
      ov[0] = sp[sub*4]; ov[1] = sp[sub*4+1]; ov[2] = sp[sub*4+2]; ov[3] = sp[sub*4+3];
      __builtin_nontemporal_store(ov, (f32x4*)(out_row + kv + sub*16 + g*4));
    }

    // ---- deferred-max online softmax ----
    float lmax = sp[0];
#pragma unroll
    for (int i = 1; i < 16; ++i) lmax = fmaxf(lmax, sp[i]);
    if (!__all(lmax <= m_run + 8.0f)) {
      float tmax = fmaxf(lmax, __shfl_xor(lmax, 16));
      tmax = fmaxf(tmax, __shfl_xor(tmax, 32));
      float mnew = fmaxf(m_run, tmax);
      float alpha = __expf(m_run - mnew);
      l_part *= alpha;
#pragma unroll
      for (int c = 0; c < 4; ++c) {
        oacc[c][0] *= alpha; oacc[c][1] *= alpha;
        oacc[c][2] *= alpha; oacc[c][3] *= alpha;
      }
      m_run = mnew;
    }
    float lsum = 0.0f;
#pragma unroll
    for (int i = 0; i < 16; ++i) { sp[i] = __expf(sp[i] - m_run); lsum += sp[i]; }
    l_part += lsum;

    union { unsigned u[2]; bf16x4 hh; } pk[4];
#pragma unroll
    for (int ks = 0; ks < 4; ++ks) {
      pk[ks].u[0] = cvtpk(sp[ks*4],   sp[ks*4+1]);
      pk[ks].u[1] = cvtpk(sp[ks*4+2], sp[ks*4+3]);
    }

    // ---- PV ----
    __builtin_amdgcn_s_setprio(1);
#pragma unroll
    for (int ks = 0; ks < 4; ++ks)
#pragma unroll
      for (int c = 0; c < 4; ++c) {
        int lbv = (c*16 + lo) * 128 + ks*32 + g*8;
        bf16x4 vf = *(const bf16x4*)(lds + 16384 + cur*8192 + SWZ(lbv));
        oacc[c] = MFMA16(vf, pk[ks].hh, oacc[c]);
      }
    __builtin_amdgcn_s_setprio(0);

    cur ^= 1;
    // barrier: retire down to 9 outstanding = exactly the 2 stage loads (+ any
    // ancient stores); this iter's bias(5)+stores(4) keep flying.
    __builtin_amdgcn_sched_barrier(0);
    asm volatile("s_waitcnt vmcnt(9)" ::: "memory");
    __builtin_amdgcn_s_barrier();
  }

  l_part += __shfl_xor(l_part, 16);
  l_part += __shfl_xor(l_part, 32);
  float inv = 1.0f / l_part;

  size_t crow = ((size_t)bb * N + qrow) * 768 + h * 64;
#pragma unroll
  for (int c = 0; c < 4; ++c) {
    ushort4 u;
    u.x = f2bf(oacc[c][0] * inv);
    u.y = f2bf(oacc[c][1] * inv);
    u.z = f2bf(oacc[c][2] * inv);
    u.w = f2bf(oacc[c][3] * inv);
    *(ushort4*)(ctx + crow + c*16 + g*4) = u;
  }
#undef STAGE
#undef SWZ
}

// ---------------- LDS-staged proj GEMM: ctx[8192,768] @ Wp[768,768]^T + b ------
__global__ __launch_bounds__(256) void gemm_proj(
    const unsigned short* __restrict__ X,
    const unsigned short* __restrict__ W,
    const float* __restrict__ bias,
    float* __restrict__ out)
{
  __shared__ unsigned short As[128*40];
  __shared__ unsigned short Bs[128*40];
  const int K = 768;
  int tid = threadIdx.x;
  int bm = blockIdx.x & 63;
  int bn = blockIdx.x >> 6;
  int wave = tid >> 6, lane = tid & 63;
  int lo = lane & 15, g = lane >> 4;
  int wr = (wave >> 1) * 64, wc = (wave & 1) * 64;
  int row0 = bm * 128, col0 = bn * 128;

  int sr = tid >> 1;
  int sc = (tid & 1) * 16;
  const unsigned short* gA = X + (size_t)(row0 + sr) * K + sc;
  const unsigned short* gB = W + (size_t)(col0 + sr) * K + sc;
  unsigned short* sA = &As[sr * 40 + sc];
  unsigned short* sB = &Bs[sr * 40 + sc];

  f32x4 acc[4][4] = {};
  for (int k0 = 0; k0 < K; k0 += 32) {
    bf16x8 a0 = *(const bf16x8*)(gA + k0);
    bf16x8 a1 = *(const bf16x8*)(gA + k0 + 8);
    bf16x8 b0 = *(const bf16x8*)(gB + k0);
    bf16x8 b1 = *(const bf16x8*)(gB + k0 + 8);
    __syncthreads();
    *(bf16x8*)(sA)     = a0;
    *(bf16x8*)(sA + 8) = a1;
    *(bf16x8*)(sB)     = b0;
    *(bf16x8*)(sB + 8) = b1;
    __syncthreads();
    bf16x8 af[4], bf[4];
#pragma unroll
    for (int i = 0; i < 4; ++i) af[i] = *(const bf16x8*)&As[(wr + i*16 + lo)*40 + g*8];
#pragma unroll
    for (int i = 0; i < 4; ++i) bf[i] = *(const bf16x8*)&Bs[(wc + i*16 + lo)*40 + g*8];
#pragma unroll
    for (int mi = 0; mi < 4; ++mi)
#pragma unroll
      for (int ni = 0; ni < 4; ++ni)
        acc[mi][ni] = MFMA32(af[mi], bf[ni], acc[mi][ni]);
  }
  int orow0 = row0 + wr, ocol0 = col0 + wc;
#pragma unroll
  for (int ni = 0; ni < 4; ++ni) {
    int col = ocol0 + ni*16 + lo;
    float bc = bias[col];
#pragma unroll
    for (int mi = 0; mi < 4; ++mi) {
#pragma unroll
      for (int r = 0; r < 4; ++r) {
        int row = orow0 + mi*16 + g*4 + r;
        out[(size_t)row * 768 + col] = acc[mi][ni][r] + bc;
      }
    }
  }
}

extern "C" void kernel_launch(void* const* d_in, const int* in_sizes, int n_in,
                              void* d_out, int out_size, void* d_ws, size_t ws_size,
                              hipStream_t stream) {
  const float* x            = (const float*)d_in[0];
  const float* rel_pos_bias = (const float*)d_in[1];
  const int* mask           = (const int*)d_in[2];
  const float* Wqkv         = (const float*)d_in[3];
  const float* bqkv         = (const float*)d_in[4];
  const float* Wproj        = (const float*)d_in[5];
  const float* bproj        = (const float*)d_in[6];

  float* out0 = (float*)d_out;                         // [8,1024,768]
  float* out1 = out0 + (size_t)8 * 1024 * 768;         // [8,12,1024,1024]

  char* ws = (char*)d_ws;
  unsigned short* xb  = (unsigned short*)(ws);            // dead after gemm_qkv -> Vt
  unsigned short* wqb = (unsigned short*)(ws + 12582912);
  unsigned short* wpb = (unsigned short*)(ws + 16121856);
  unsigned short* Qb  = (unsigned short*)(ws + 17301504);
  unsigned short* Kb  = (unsigned short*)(ws + 29884416);
  unsigned short* Vb  = (unsigned short*)(ws + 42467328);
  unsigned short* ctx = (unsigned short*)(ws + 55050240);
  unsigned short* Vtb = xb;
  unsigned long long* mbits = (unsigned long long*)(ws + 67633152); // 1 MB

  cvt_mask<<<10496, 256, 0, stream>>>(x, Wqkv, Wproj, xb, mask, mbits);

  gemm_qkv<<<1152, 256, 0, stream>>>(xb, wqb, bqkv, Qb, Kb, Vb);

  vtrans<<<dim3(16, 96), 256, 0, stream>>>(Vb, Vtb);

  attn_kernel<<<dim3(8, 96), 512, 0, stream>>>(Qb, Kb, Vtb, rel_pos_bias,
                                               (const unsigned*)mbits, out1, ctx);

  gemm_proj<<<384, 256, 0, stream>>>(ctx, wpb, bproj, out0);
}

// Round 11
// 247.100 us; speedup vs baseline: 2.0855x; 2.0855x over previous
//
#include <hip/hip_runtime.h>
#include <hip/hip_bf16.h>

typedef __attribute__((ext_vector_type(8))) short bf16x8;
typedef __attribute__((ext_vector_type(4))) short bf16x4;
typedef __attribute__((ext_vector_type(4))) float f32x4;

#define MFMA32(a,b,c) __builtin_amdgcn_mfma_f32_16x16x32_bf16(a,b,c,0,0,0)

#if __has_builtin(__builtin_amdgcn_mfma_f32_16x16x16bf16_1k)
#define MFMA16(a,b,c) __builtin_amdgcn_mfma_f32_16x16x16bf16_1k(a,b,c,0,0,0)
#else
static __device__ __forceinline__ f32x4 mfma16_asm(bf16x4 a, bf16x4 b, f32x4 c){
  asm volatile("v_mfma_f32_16x16x16_bf16 %0, %1, %2, %0" : "+v"(c) : "v"(a), "v"(b));
  return c;
}
#define MFMA16(a,b,c) mfma16_asm(a,b,c)
#endif

#define NEGV -65504.0f

__device__ __forceinline__ unsigned short f2bf(float f){
  union { float f; unsigned u; } x; x.f = f;
  unsigned r = x.u + 0x7fffu + ((x.u >> 16) & 1u);
  return (unsigned short)(r >> 16);
}

__device__ __forceinline__ unsigned cvtpk(float a, float b){
  unsigned r;
  asm volatile("v_cvt_pk_bf16_f32 %0, %1, %2" : "=v"(r) : "v"(a), "v"(b));
  return r;   // a -> low 16, b -> high 16
}

// ---------------- mask int32 -> bitmask (1 bit per element) ----------------
__global__ __launch_bounds__(256) void mask_to_bits(const int* __restrict__ m,
                                                    unsigned long long* __restrict__ out){
  int gw = (blockIdx.x * 256 + threadIdx.x) >> 6;
  int lane = threadIdx.x & 63;
#pragma unroll
  for (int stp = 0; stp < 16; ++stp) {
    size_t base = ((size_t)gw * 16 + stp) * 64;
    int v = m[base + lane];
    unsigned long long bb = __ballot(v != 0);
    if (lane == 0) out[base >> 6] = bb;
  }
}

// ------- LDS-staged QKV GEMM, fp32 inputs staged with on-the-fly bf16 convert ---
// X32[8192,768] fp32 @ W32[2304,768]^T fp32 + b -> q(x0.125)->Qd, k->Kd, v->Vd
__global__ __launch_bounds__(256) void gemm_qkv(
    const float* __restrict__ X32,
    const float* __restrict__ W32,
    const float* __restrict__ bias,
    unsigned short* __restrict__ Qd,
    unsigned short* __restrict__ Kd,
    unsigned short* __restrict__ Vd)
{
  __shared__ unsigned short As[128*40];
  __shared__ unsigned short Bs[128*40];
  const int K = 768;
  int tid = threadIdx.x;
  int bm = blockIdx.x & 63;
  int bn = blockIdx.x >> 6;
  int wave = tid >> 6, lane = tid & 63;
  int lo = lane & 15, g = lane >> 4;
  int wr = (wave >> 1) * 64, wc = (wave & 1) * 64;
  int row0 = bm * 128, col0 = bn * 128;

  int sr = tid >> 1;                  // 0..127
  int sc = (tid & 1) * 16;            // 0 or 16 (elements)
  const float* gA = X32 + (size_t)(row0 + sr) * K + sc;
  const float* gB = W32 + (size_t)(col0 + sr) * K + sc;
  unsigned* sA = (unsigned*)&As[sr * 40 + sc];
  unsigned* sB = (unsigned*)&Bs[sr * 40 + sc];

  f32x4 acc[4][4] = {};
  for (int k0 = 0; k0 < K; k0 += 32) {
    float4 a0 = *(const float4*)(gA + k0);
    float4 a1 = *(const float4*)(gA + k0 + 4);
    float4 a2 = *(const float4*)(gA + k0 + 8);
    float4 a3 = *(const float4*)(gA + k0 + 12);
    float4 b0 = *(const float4*)(gB + k0);
    float4 b1 = *(const float4*)(gB + k0 + 4);
    float4 b2 = *(const float4*)(gB + k0 + 8);
    float4 b3 = *(const float4*)(gB + k0 + 12);
    __syncthreads();
    sA[0] = cvtpk(a0.x, a0.y); sA[1] = cvtpk(a0.z, a0.w);
    sA[2] = cvtpk(a1.x, a1.y); sA[3] = cvtpk(a1.z, a1.w);
    sA[4] = cvtpk(a2.x, a2.y); sA[5] = cvtpk(a2.z, a2.w);
    sA[6] = cvtpk(a3.x, a3.y); sA[7] = cvtpk(a3.z, a3.w);
    sB[0] = cvtpk(b0.x, b0.y); sB[1] = cvtpk(b0.z, b0.w);
    sB[2] = cvtpk(b1.x, b1.y); sB[3] = cvtpk(b1.z, b1.w);
    sB[4] = cvtpk(b2.x, b2.y); sB[5] = cvtpk(b2.z, b2.w);
    sB[6] = cvtpk(b3.x, b3.y); sB[7] = cvtpk(b3.z, b3.w);
    __syncthreads();
    bf16x8 af[4], bf[4];
#pragma unroll
    for (int i = 0; i < 4; ++i) af[i] = *(const bf16x8*)&As[(wr + i*16 + lo)*40 + g*8];
#pragma unroll
    for (int i = 0; i < 4; ++i) bf[i] = *(const bf16x8*)&Bs[(wc + i*16 + lo)*40 + g*8];
#pragma unroll
    for (int mi = 0; mi < 4; ++mi)
#pragma unroll
      for (int ni = 0; ni < 4; ++ni)
        acc[mi][ni] = MFMA32(af[mi], bf[ni], acc[mi][ni]);
  }
  int orow0 = row0 + wr, ocol0 = col0 + wc;
#pragma unroll
  for (int ni = 0; ni < 4; ++ni) {
    int col = ocol0 + ni*16 + lo;
    float bc = bias[col];
    int which = col / 768;
    int rem = col - which * 768;
    int h = rem >> 6, d = rem & 63;
    unsigned short* dst = (which == 0) ? Qd : (which == 1) ? Kd : Vd;
    float scale = (which == 0) ? 0.125f : 1.0f;
#pragma unroll
    for (int mi = 0; mi < 4; ++mi) {
#pragma unroll
      for (int r = 0; r < 4; ++r) {
        int row = orow0 + mi*16 + g*4 + r;
        int bb = row >> 10, n = row & 1023;
        dst[(((size_t)bb*12 + h)*1024 + n)*64 + d] = f2bf((acc[mi][ni][r] + bc) * scale);
      }
    }
  }
}

// ---------------- V transpose: [96][1024][64] -> [96][64][1024] ----------------
__global__ __launch_bounds__(256) void vtrans(const unsigned short* __restrict__ V,
                                              unsigned short* __restrict__ Vt){
  __shared__ unsigned short t[64][72];
  int bh = blockIdx.y;
  int n0 = blockIdx.x * 64;
  int tid = threadIdx.x;
  int nl = tid >> 2;
  int dq = (tid & 3) * 16;
  const unsigned short* src = V + ((size_t)bh*1024 + n0 + nl)*64 + dq;
  bf16x8 a0 = *(const bf16x8*)(src);
  bf16x8 a1 = *(const bf16x8*)(src + 8);
  *(bf16x8*)&t[nl][dq]     = a0;
  *(bf16x8*)&t[nl][dq + 8] = a1;
  __syncthreads();
  int d  = tid >> 2;
  int nq = (tid & 3) * 16;
  union { unsigned short s[16]; bf16x8 v[2]; } pk;
#pragma unroll
  for (int j = 0; j < 16; ++j) pk.s[j] = t[nq + j][d];
  unsigned short* dst = Vt + ((size_t)bh*64 + d)*1024 + n0 + nq;
  *(bf16x8*)(dst)     = pk.v[0];
  *(bf16x8*)(dst + 8) = pk.v[1];
}

// ---------------- fused attention core (exact R7 structure, proven best) -------
__global__ __launch_bounds__(512, 4) void attn_kernel(
    const unsigned short* __restrict__ Qd,
    const unsigned short* __restrict__ Kd,
    const unsigned short* __restrict__ Vt,     // [96][64][1024]
    const float* __restrict__ bias,            // [12,1024,1024] fp32
    const unsigned* __restrict__ maskbits,     // [8*1024][32] u32 words
    float* __restrict__ out1,                  // [96,1024,1024] fp32
    unsigned short* __restrict__ ctx)          // [8192,768] bf16
{
  __shared__ char lds[32768];
  const int N = 1024, D = 64;
  int y = blockIdx.y;
  int h = y >> 3, bb = y & 7;
  int bh = bb * 12 + h;
  int tid = threadIdx.x;
  int wave = tid >> 6, lane = tid & 63;
  int lo = lane & 15, g = lane >> 4;
  int qrow = blockIdx.x * 128 + wave * 16 + lo;

  const size_t qoff = ((size_t)bh * N + qrow) * D;
  bf16x8 qf0 = *(const bf16x8*)(Qd + qoff + g*8);
  bf16x8 qf1 = *(const bf16x8*)(Qd + qoff + 32 + g*8);

  const float* bias_row = bias + ((size_t)h * N + qrow) * N;
  const unsigned* mrow  = maskbits + ((size_t)bb * N + qrow) * 32;
  float* out_row        = out1 + ((size_t)bh * N + qrow) * N;

  int o  = tid * 16;
  int sw = o ^ (((o >> 7) & 7) << 4);
  const char* kbase = (const char*)(Kd + (size_t)bh * N * D);
  const char* vbase = (const char*)(Vt + (size_t)bh * D * N);
  const char* ksrc  = kbase + sw;                           // + kv*128 per tile
  const char* vsrc  = vbase + (o >> 7) * 2048 + (sw & 127); // + kv*2 per tile
  int wbase = wave << 10;

#define STAGE(buf, kv) do { \
    __builtin_amdgcn_global_load_lds( \
      (const __attribute__((address_space(1))) unsigned*)(ksrc + (size_t)(kv)*128), \
      (__attribute__((address_space(3))) unsigned*)(lds + (buf)*8192 + wbase), 16, 0, 0); \
    __builtin_amdgcn_global_load_lds( \
      (const __attribute__((address_space(1))) unsigned*)(vsrc + (size_t)(kv)*2), \
      (__attribute__((address_space(3))) unsigned*)(lds + 16384 + (buf)*8192 + wbase), 16, 0, 0); \
  } while (0)

#define SWZ(lb) ((lb) ^ ((((lb) >> 7) & 7) << 4))

  float m_run = -INFINITY, l_part = 0.0f;
  f32x4 oacc[4] = {};   // O^T: lane holds q=lo, d = c*16 + g*4 + reg

  STAGE(0, 0);
  __syncthreads();
  int cur = 0;

  for (int it = 0; it < 16; ++it) {
    int kv = it * 64;
    if (it < 15) STAGE(cur ^ 1, kv + 64);
    __builtin_amdgcn_sched_barrier(0);

    unsigned mw0 = mrow[it*2];
    unsigned mw1 = mrow[it*2 + 1];

    f32x4 s[4];
    __builtin_amdgcn_s_setprio(1);
#pragma unroll
    for (int sub = 0; sub < 4; ++sub) {
      int lbr = (sub*16 + lo) * 128 + g*16;
      bf16x8 k0 = *(const bf16x8*)(lds + cur*8192 + SWZ(lbr));
      bf16x8 k1 = *(const bf16x8*)(lds + cur*8192 + SWZ(lbr + 64));
      f32x4 t = {};
      t = MFMA32(k0, qf0, t);
      t = MFMA32(k1, qf1, t);
      s[sub] = t;
    }
    __builtin_amdgcn_s_setprio(0);

    float sp[16];
#pragma unroll
    for (int sub = 0; sub < 4; ++sub) {
      f32x4 bi = *(const f32x4*)(bias_row + kv + sub*16 + g*4);
      unsigned mw = (sub < 2) ? mw0 : mw1;
      int sh = (sub & 1) * 16 + g * 4;
#pragma unroll
      for (int r = 0; r < 4; ++r)
        sp[sub*4+r] = (((mw >> (sh + r)) & 1u) ? NEGV : s[sub][r]) + bi[r];
      f32x4 ov;
      ov[0] = sp[sub*4]; ov[1] = sp[sub*4+1]; ov[2] = sp[sub*4+2]; ov[3] = sp[sub*4+3];
      __builtin_nontemporal_store(ov, (f32x4*)(out_row + kv + sub*16 + g*4));
    }

    float lmax = sp[0];
#pragma unroll
    for (int i = 1; i < 16; ++i) lmax = fmaxf(lmax, sp[i]);
    if (!__all(lmax <= m_run + 8.0f)) {
      float tmax = fmaxf(lmax, __shfl_xor(lmax, 16));
      tmax = fmaxf(tmax, __shfl_xor(tmax, 32));
      float mnew = fmaxf(m_run, tmax);
      float alpha = __expf(m_run - mnew);
      l_part *= alpha;
#pragma unroll
      for (int c = 0; c < 4; ++c) {
        oacc[c][0] *= alpha; oacc[c][1] *= alpha;
        oacc[c][2] *= alpha; oacc[c][3] *= alpha;
      }
      m_run = mnew;
    }
    float lsum = 0.0f;
#pragma unroll
    for (int i = 0; i < 16; ++i) { sp[i] = __expf(sp[i] - m_run); lsum += sp[i]; }
    l_part += lsum;

    union { unsigned u[2]; bf16x4 hh; } pk[4];
#pragma unroll
    for (int ks = 0; ks < 4; ++ks) {
      pk[ks].u[0] = cvtpk(sp[ks*4],   sp[ks*4+1]);
      pk[ks].u[1] = cvtpk(sp[ks*4+2], sp[ks*4+3]);
    }

    __builtin_amdgcn_s_setprio(1);
#pragma unroll
    for (int ks = 0; ks < 4; ++ks)
#pragma unroll
      for (int c = 0; c < 4; ++c) {
        int lbv = (c*16 + lo) * 128 + ks*32 + g*8;
        bf16x4 vf = *(const bf16x4*)(lds + 16384 + cur*8192 + SWZ(lbv));
        oacc[c] = MFMA16(vf, pk[ks].hh, oacc[c]);
      }
    __builtin_amdgcn_s_setprio(0);

    cur ^= 1;
    __builtin_amdgcn_sched_barrier(0);
    asm volatile("s_waitcnt vmcnt(4)" ::: "memory");
    __builtin_amdgcn_s_barrier();
  }

  l_part += __shfl_xor(l_part, 16);
  l_part += __shfl_xor(l_part, 32);
  float inv = 1.0f / l_part;

  size_t crow = ((size_t)bb * N + qrow) * 768 + h * 64;
#pragma unroll
  for (int c = 0; c < 4; ++c) {
    ushort4 u;
    u.x = f2bf(oacc[c][0] * inv);
    u.y = f2bf(oacc[c][1] * inv);
    u.z = f2bf(oacc[c][2] * inv);
    u.w = f2bf(oacc[c][3] * inv);
    *(ushort4*)(ctx + crow + c*16 + g*4) = u;
  }
#undef STAGE
#undef SWZ
}

// ------- LDS-staged proj GEMM: ctx bf16 @ Wp32 fp32^T (on-the-fly cvt) + b -----
__global__ __launch_bounds__(256) void gemm_proj(
    const unsigned short* __restrict__ X,
    const float* __restrict__ W32,
    const float* __restrict__ bias,
    float* __restrict__ out)
{
  __shared__ unsigned short As[128*40];
  __shared__ unsigned short Bs[128*40];
  const int K = 768;
  int tid = threadIdx.x;
  int bm = blockIdx.x & 63;
  int bn = blockIdx.x >> 6;
  int wave = tid >> 6, lane = tid & 63;
  int lo = lane & 15, g = lane >> 4;
  int wr = (wave >> 1) * 64, wc = (wave & 1) * 64;
  int row0 = bm * 128, col0 = bn * 128;

  int sr = tid >> 1;
  int sc = (tid & 1) * 16;
  const unsigned short* gA = X + (size_t)(row0 + sr) * K + sc;
  const float* gB = W32 + (size_t)(col0 + sr) * K + sc;
  unsigned short* sA = &As[sr * 40 + sc];
  unsigned* sB = (unsigned*)&Bs[sr * 40 + sc];

  f32x4 acc[4][4] = {};
  for (int k0 = 0; k0 < K; k0 += 32) {
    bf16x8 a0 = *(const bf16x8*)(gA + k0);
    bf16x8 a1 = *(const bf16x8*)(gA + k0 + 8);
    float4 b0 = *(const float4*)(gB + k0);
    float4 b1 = *(const float4*)(gB + k0 + 4);
    float4 b2 = *(const float4*)(gB + k0 + 8);
    float4 b3 = *(const float4*)(gB + k0 + 12);
    __syncthreads();
    *(bf16x8*)(sA)     = a0;
    *(bf16x8*)(sA + 8) = a1;
    sB[0] = cvtpk(b0.x, b0.y); sB[1] = cvtpk(b0.z, b0.w);
    sB[2] = cvtpk(b1.x, b1.y); sB[3] = cvtpk(b1.z, b1.w);
    sB[4] = cvtpk(b2.x, b2.y); sB[5] = cvtpk(b2.z, b2.w);
    sB[6] = cvtpk(b3.x, b3.y); sB[7] = cvtpk(b3.z, b3.w);
    __syncthreads();
    bf16x8 af[4], bf[4];
#pragma unroll
    for (int i = 0; i < 4; ++i) af[i] = *(const bf16x8*)&As[(wr + i*16 + lo)*40 + g*8];
#pragma unroll
    for (int i = 0; i < 4; ++i) bf[i] = *(const bf16x8*)&Bs[(wc + i*16 + lo)*40 + g*8];
#pragma unroll
    for (int mi = 0; mi < 4; ++mi)
#pragma unroll
      for (int ni = 0; ni < 4; ++ni)
        acc[mi][ni] = MFMA32(af[mi], bf[ni], acc[mi][ni]);
  }
  int orow0 = row0 + wr, ocol0 = col0 + wc;
#pragma unroll
  for (int ni = 0; ni < 4; ++ni) {
    int col = ocol0 + ni*16 + lo;
    float bc = bias[col];
#pragma unroll
    for (int mi = 0; mi < 4; ++mi) {
#pragma unroll
      for (int r = 0; r < 4; ++r) {
        int row = orow0 + mi*16 + g*4 + r;
        out[(size_t)row * 768 + col] = acc[mi][ni][r] + bc;
      }
    }
  }
}

extern "C" void kernel_launch(void* const* d_in, const int* in_sizes, int n_in,
                              void* d_out, int out_size, void* d_ws, size_t ws_size,
                              hipStream_t stream) {
  const float* x            = (const float*)d_in[0];
  const float* rel_pos_bias = (const float*)d_in[1];
  const int* mask           = (const int*)d_in[2];
  const float* Wqkv         = (const float*)d_in[3];
  const float* bqkv         = (const float*)d_in[4];
  const float* Wproj        = (const float*)d_in[5];
  const float* bproj        = (const float*)d_in[6];

  float* out0 = (float*)d_out;                         // [8,1024,768]
  float* out1 = out0 + (size_t)8 * 1024 * 768;         // [8,12,1024,1024]

  char* ws = (char*)d_ws;
  unsigned short* Vtb = (unsigned short*)(ws);            // V^T (vtrans output)
  unsigned short* Qb  = (unsigned short*)(ws + 17301504);
  unsigned short* Kb  = (unsigned short*)(ws + 29884416);
  unsigned short* Vb  = (unsigned short*)(ws + 42467328);
  unsigned short* ctx = (unsigned short*)(ws + 55050240);
  unsigned long long* mbits = (unsigned long long*)(ws + 67633152); // 1 MB

  mask_to_bits<<<2048, 256, 0, stream>>>(mask, mbits);

  gemm_qkv<<<1152, 256, 0, stream>>>(x, Wqkv, bqkv, Qb, Kb, Vb);

  vtrans<<<dim3(16, 96), 256, 0, stream>>>(Vb, Vtb);

  attn_kernel<<<dim3(8, 96), 512, 0, stream>>>(Qb, Kb, Vtb, rel_pos_bias,
                                               (const unsigned*)mbits, out1, ctx);

  gemm_proj<<<384, 256, 0, stream>>>(ctx, Wproj, bproj, out0);
}

// Round 12
// 246.539 us; speedup vs baseline: 2.0903x; 1.0023x over previous
//
#include <hip/hip_runtime.h>
#include <hip/hip_bf16.h>

typedef __attribute__((ext_vector_type(8))) short bf16x8;
typedef __attribute__((ext_vector_type(4))) short bf16x4;
typedef __attribute__((ext_vector_type(4))) float f32x4;

#define MFMA32(a,b,c) __builtin_amdgcn_mfma_f32_16x16x32_bf16(a,b,c,0,0,0)

#if __has_builtin(__builtin_amdgcn_mfma_f32_16x16x16bf16_1k)
#define MFMA16(a,b,c) __builtin_amdgcn_mfma_f32_16x16x16bf16_1k(a,b,c,0,0,0)
#else
static __device__ __forceinline__ f32x4 mfma16_asm(bf16x4 a, bf16x4 b, f32x4 c){
  asm volatile("v_mfma_f32_16x16x16_bf16 %0, %1, %2, %0" : "+v"(c) : "v"(a), "v"(b));
  return c;
}
#define MFMA16(a,b,c) mfma16_asm(a,b,c)
#endif

#define NEGV -65504.0f

__device__ __forceinline__ unsigned short f2bf(float f){
  union { float f; unsigned u; } x; x.f = f;
  unsigned r = x.u + 0x7fffu + ((x.u >> 16) & 1u);
  return (unsigned short)(r >> 16);
}

__device__ __forceinline__ float bf2f(unsigned short s){
  union { unsigned u; float f; } c; c.u = ((unsigned)s) << 16; return c.f;
}

__device__ __forceinline__ unsigned cvtpk(float a, float b){
  unsigned r;
  asm volatile("v_cvt_pk_bf16_f32 %0, %1, %2" : "=v"(r) : "v"(a), "v"(b));
  return r;   // a -> low 16, b -> high 16
}

// ---------------- fused fp32 -> bf16 convert for x, W_qkv, W_proj ----------------
__global__ __launch_bounds__(256) void cvt_all(
    const float* __restrict__ x, const float* __restrict__ wq,
    const float* __restrict__ wp, unsigned short* __restrict__ out){
  int i = blockIdx.x * 256 + threadIdx.x;
  const float* src; int j;
  if (i < 1572864)      { src = x;  j = i; }
  else if (i < 2015232) { src = wq; j = i - 1572864; }
  else                  { src = wp; j = i - 2015232; }
  float4 f = ((const float4*)src)[j];
  ushort4 u;
  u.x = f2bf(f.x); u.y = f2bf(f.y); u.z = f2bf(f.z); u.w = f2bf(f.w);
  ((ushort4*)out)[i] = u;
}

// ---------------- bias fp32 -> bf16 (only when ws has room) ----------------
__global__ __launch_bounds__(256) void cvt_bias(const float* __restrict__ in,
                                                unsigned short* __restrict__ out){
  int i = blockIdx.x * 256 + threadIdx.x;    // 3,145,728 float4 groups
  float4 f = ((const float4*)in)[i];
  ushort4 u;
  u.x = f2bf(f.x); u.y = f2bf(f.y); u.z = f2bf(f.z); u.w = f2bf(f.w);
  ((ushort4*)out)[i] = u;
}

// ---------------- mask int32 -> bitmask (1 bit per element) ----------------
__global__ __launch_bounds__(256) void mask_to_bits(const int* __restrict__ m,
                                                    unsigned long long* __restrict__ out){
  int gw = (blockIdx.x * 256 + threadIdx.x) >> 6;
  int lane = threadIdx.x & 63;
#pragma unroll
  for (int stp = 0; stp < 16; ++stp) {
    size_t base = ((size_t)gw * 16 + stp) * 64;
    int v = m[base + lane];
    unsigned long long bb = __ballot(v != 0);
    if (lane == 0) out[base >> 6] = bb;
  }
}

// ---------------- LDS-staged QKV GEMM: X[8192,768] @ W[2304,768]^T + b ----------
__global__ __launch_bounds__(256) void gemm_qkv(
    const unsigned short* __restrict__ X,
    const unsigned short* __restrict__ W,
    const float* __restrict__ bias,
    unsigned short* __restrict__ Qd,
    unsigned short* __restrict__ Kd,
    unsigned short* __restrict__ Vd)
{
  __shared__ unsigned short As[128*40];
  __shared__ unsigned short Bs[128*40];
  const int K = 768;
  int tid = threadIdx.x;
  int bm = blockIdx.x & 63;
  int bn = blockIdx.x >> 6;
  int wave = tid >> 6, lane = tid & 63;
  int lo = lane & 15, g = lane >> 4;
  int wr = (wave >> 1) * 64, wc = (wave & 1) * 64;
  int row0 = bm * 128, col0 = bn * 128;

  int sr = tid >> 1;
  int sc = (tid & 1) * 16;
  const unsigned short* gA = X + (size_t)(row0 + sr) * K + sc;
  const unsigned short* gB = W + (size_t)(col0 + sr) * K + sc;
  unsigned short* sA = &As[sr * 40 + sc];
  unsigned short* sB = &Bs[sr * 40 + sc];

  f32x4 acc[4][4] = {};
  for (int k0 = 0; k0 < K; k0 += 32) {
    bf16x8 a0 = *(const bf16x8*)(gA + k0);
    bf16x8 a1 = *(const bf16x8*)(gA + k0 + 8);
    bf16x8 b0 = *(const bf16x8*)(gB + k0);
    bf16x8 b1 = *(const bf16x8*)(gB + k0 + 8);
    __syncthreads();
    *(bf16x8*)(sA)     = a0;
    *(bf16x8*)(sA + 8) = a1;
    *(bf16x8*)(sB)     = b0;
    *(bf16x8*)(sB + 8) = b1;
    __syncthreads();
    bf16x8 af[4], bf[4];
#pragma unroll
    for (int i = 0; i < 4; ++i) af[i] = *(const bf16x8*)&As[(wr + i*16 + lo)*40 + g*8];
#pragma unroll
    for (int i = 0; i < 4; ++i) bf[i] = *(const bf16x8*)&Bs[(wc + i*16 + lo)*40 + g*8];
#pragma unroll
    for (int mi = 0; mi < 4; ++mi)
#pragma unroll
      for (int ni = 0; ni < 4; ++ni)
        acc[mi][ni] = MFMA32(af[mi], bf[ni], acc[mi][ni]);
  }
  int orow0 = row0 + wr, ocol0 = col0 + wc;
#pragma unroll
  for (int ni = 0; ni < 4; ++ni) {
    int col = ocol0 + ni*16 + lo;
    float bc = bias[col];
    int which = col / 768;
    int rem = col - which * 768;
    int h = rem >> 6, d = rem & 63;
    unsigned short* dst = (which == 0) ? Qd : (which == 1) ? Kd : Vd;
    float scale = (which == 0) ? 0.125f : 1.0f;
#pragma unroll
    for (int mi = 0; mi < 4; ++mi) {
#pragma unroll
      for (int r = 0; r < 4; ++r) {
        int row = orow0 + mi*16 + g*4 + r;
        int bb = row >> 10, n = row & 1023;
        dst[(((size_t)bb*12 + h)*1024 + n)*64 + d] = f2bf((acc[mi][ni][r] + bc) * scale);
      }
    }
  }
}

// ---------------- V transpose: [96][1024][64] -> [96][64][1024] ----------------
__global__ __launch_bounds__(256) void vtrans(const unsigned short* __restrict__ V,
                                              unsigned short* __restrict__ Vt){
  __shared__ unsigned short t[64][72];
  int bh = blockIdx.y;
  int n0 = blockIdx.x * 64;
  int tid = threadIdx.x;
  int nl = tid >> 2;
  int dq = (tid & 3) * 16;
  const unsigned short* src = V + ((size_t)bh*1024 + n0 + nl)*64 + dq;
  bf16x8 a0 = *(const bf16x8*)(src);
  bf16x8 a1 = *(const bf16x8*)(src + 8);
  *(bf16x8*)&t[nl][dq]     = a0;
  *(bf16x8*)&t[nl][dq + 8] = a1;
  __syncthreads();
  int d  = tid >> 2;
  int nq = (tid & 3) * 16;
  union { unsigned short s[16]; bf16x8 v[2]; } pk;
#pragma unroll
  for (int j = 0; j < 16; ++j) pk.s[j] = t[nq + j][d];
  unsigned short* dst = Vt + ((size_t)bh*64 + d)*1024 + n0 + nq;
  *(bf16x8*)(dst)     = pk.v[0];
  *(bf16x8*)(dst + 8) = pk.v[1];
}

// ---------------- fused attention core, 8 waves x 16 q-rows, LDS-shared K/V ----
// R7 structure + R10 rotation: bias/mask(it+1) issued BETWEEN masked-add and
// stores(it) -> stores are perpetually the newest vmem ops; barrier vmcnt(9)
// keeps exactly {stores(4) + bias/mask(5)} in flight and waits only on stage.
// BB=1: bias read as bf16 (halves the dominant read stream).
template<int BB>
__global__ __launch_bounds__(512, 4) void attn_kernel(
    const unsigned short* __restrict__ Qd,
    const unsigned short* __restrict__ Kd,
    const unsigned short* __restrict__ Vt,     // [96][64][1024]
    const void* __restrict__ biasp,            // [12,1024,1024] fp32 or bf16
    const unsigned* __restrict__ maskbits,     // [8*1024][32] u32 words
    float* __restrict__ out1,                  // [96,1024,1024] fp32
    unsigned short* __restrict__ ctx)          // [8192,768] bf16
{
  __shared__ char lds[32768];
  const int N = 1024, D = 64;
  int y = blockIdx.y;
  int h = y >> 3, bb = y & 7;
  int bh = bb * 12 + h;
  int tid = threadIdx.x;
  int wave = tid >> 6, lane = tid & 63;
  int lo = lane & 15, g = lane >> 4;
  int qrow = blockIdx.x * 128 + wave * 16 + lo;

  const size_t qoff = ((size_t)bh * N + qrow) * D;
  bf16x8 qf0 = *(const bf16x8*)(Qd + qoff + g*8);
  bf16x8 qf1 = *(const bf16x8*)(Qd + qoff + 32 + g*8);

  const float* brf = (const float*)biasp + ((size_t)h * N + qrow) * N;
  const unsigned short* brh = (const unsigned short*)biasp + ((size_t)h * N + qrow) * N;
  const unsigned* mrow  = maskbits + ((size_t)bb * N + qrow) * 32;
  float* out_row        = out1 + ((size_t)bh * N + qrow) * N;

  int o  = tid * 16;
  int sw = o ^ (((o >> 7) & 7) << 4);
  const char* kbase = (const char*)(Kd + (size_t)bh * N * D);
  const char* vbase = (const char*)(Vt + (size_t)bh * D * N);
  const char* ksrc  = kbase + sw;                           // + kv*128 per tile
  const char* vsrc  = vbase + (o >> 7) * 2048 + (sw & 127); // + kv*2 per tile
  int wbase = wave << 10;

#define STAGE(buf, kv) do { \
    __builtin_amdgcn_global_load_lds( \
      (const __attribute__((address_space(1))) unsigned*)(ksrc + (size_t)(kv)*128), \
      (__attribute__((address_space(3))) unsigned*)(lds + (buf)*8192 + wbase), 16, 0, 0); \
    __builtin_amdgcn_global_load_lds( \
      (const __attribute__((address_space(1))) unsigned*)(vsrc + (size_t)(kv)*2), \
      (__attribute__((address_space(3))) unsigned*)(lds + 16384 + (buf)*8192 + wbase), 16, 0, 0); \
  } while (0)

#define SWZ(lb) ((lb) ^ ((((lb) >> 7) & 7) << 4))

#define LOADBIAS(kvx) do { \
    if constexpr (BB) { \
      _Pragma("unroll") for (int sub = 0; sub < 4; ++sub) \
        bih[sub] = *(const bf16x4*)(brh + (kvx) + sub*16 + g*4); \
    } else { \
      _Pragma("unroll") for (int sub = 0; sub < 4; ++sub) \
        bif[sub] = *(const f32x4*)(brf + (kvx) + sub*16 + g*4); \
    } \
  } while (0)

  float m_run = -INFINITY, l_part = 0.0f;
  f32x4 oacc[4] = {};   // O^T: lane holds q=lo, d = c*16 + g*4 + reg

  f32x4 bif[4]; bf16x4 bih[4];
  uint2 mw = *(const uint2*)(mrow);
  LOADBIAS(0);
  STAGE(0, 0);
  __syncthreads();
  int cur = 0;

  for (int it = 0; it < 16; ++it) {
    int kv = it * 64;
    int kvn = ((it + 1) & 15) << 6;      // it=15 wraps: harmless re-stage of tile 0

    // ---- next-tile stage FIRST (oldest vmem of this iter) ----
    STAGE(cur ^ 1, kvn);
    __builtin_amdgcn_sched_barrier(0);

    // ---- QK^T: s[sub][r] = S[q=lo][kv + sub*16 + g*4 + r] ----
    f32x4 s[4];
    __builtin_amdgcn_s_setprio(1);
#pragma unroll
    for (int sub = 0; sub < 4; ++sub) {
      int lbr = (sub*16 + lo) * 128 + g*16;
      bf16x8 k0 = *(const bf16x8*)(lds + cur*8192 + SWZ(lbr));
      bf16x8 k1 = *(const bf16x8*)(lds + cur*8192 + SWZ(lbr + 64));
      f32x4 t = {};
      t = MFMA32(k0, qf0, t);
      t = MFMA32(k1, qf1, t);
      s[sub] = t;
    }
    __builtin_amdgcn_s_setprio(0);

    // ---- masked-add: consumes PRE-LOADED bi/mw (their loads are older than
    //      stage(it+1) and NEWER than stores(it-1) -> no store drain) ----
    float sp[16];
#pragma unroll
    for (int sub = 0; sub < 4; ++sub) {
      unsigned mws = (sub < 2) ? mw.x : mw.y;
      int sh = (sub & 1) * 16 + g * 4;
#pragma unroll
      for (int r = 0; r < 4; ++r) {
        float bv = BB ? bf2f((unsigned short)bih[sub][r]) : bif[sub][r];
        sp[sub*4+r] = (((mws >> (sh + r)) & 1u) ? NEGV : s[sub][r]) + bv;
      }
    }
    __builtin_amdgcn_sched_barrier(0);

    // ---- issue NEXT iter's bias/mask now (older than the stores below) ----
    mw = *(const uint2*)(mrow + (kvn >> 5));
    LOADBIAS(kvn);
    __builtin_amdgcn_sched_barrier(0);

    // ---- out1 dump (NT, perpetually-newest -> never awaited) ----
#pragma unroll
    for (int sub = 0; sub < 4; ++sub) {
      f32x4 ov;
      ov[0] = sp[sub*4]; ov[1] = sp[sub*4+1]; ov[2] = sp[sub*4+2]; ov[3] = sp[sub*4+3];
      __builtin_nontemporal_store(ov, (f32x4*)(out_row + kv + sub*16 + g*4));
    }

    // ---- deferred-max online softmax ----
    float lmax = sp[0];
#pragma unroll
    for (int i = 1; i < 16; ++i) lmax = fmaxf(lmax, sp[i]);
    if (!__all(lmax <= m_run + 8.0f)) {
      float tmax = fmaxf(lmax, __shfl_xor(lmax, 16));
      tmax = fmaxf(tmax, __shfl_xor(tmax, 32));
      float mnew = fmaxf(m_run, tmax);
      float alpha = __expf(m_run - mnew);
      l_part *= alpha;
#pragma unroll
      for (int c = 0; c < 4; ++c) {
        oacc[c][0] *= alpha; oacc[c][1] *= alpha;
        oacc[c][2] *= alpha; oacc[c][3] *= alpha;
      }
      m_run = mnew;
    }
    float lsum = 0.0f;
#pragma unroll
    for (int i = 0; i < 16; ++i) { sp[i] = __expf(sp[i] - m_run); lsum += sp[i]; }
    l_part += lsum;

    union { unsigned u[2]; bf16x4 hh; } pk[4];
#pragma unroll
    for (int ks = 0; ks < 4; ++ks) {
      pk[ks].u[0] = cvtpk(sp[ks*4],   sp[ks*4+1]);
      pk[ks].u[1] = cvtpk(sp[ks*4+2], sp[ks*4+3]);
    }

    // ---- PV ----
    __builtin_amdgcn_s_setprio(1);
#pragma unroll
    for (int ks = 0; ks < 4; ++ks)
#pragma unroll
      for (int c = 0; c < 4; ++c) {
        int lbv = (c*16 + lo) * 128 + ks*32 + g*8;
        bf16x4 vf = *(const bf16x4*)(lds + 16384 + cur*8192 + SWZ(lbv));
        oacc[c] = MFMA16(vf, pk[ks].hh, oacc[c]);
      }
    __builtin_amdgcn_s_setprio(0);

    cur ^= 1;
    // barrier: keep newest 9 = stores(4) + bias/mask(5); stage(it+1) retired.
    __builtin_amdgcn_sched_barrier(0);
    asm volatile("s_waitcnt vmcnt(9)" ::: "memory");
    __builtin_amdgcn_s_barrier();
  }

  l_part += __shfl_xor(l_part, 16);
  l_part += __shfl_xor(l_part, 32);
  float inv = 1.0f / l_part;

  size_t crow = ((size_t)bb * N + qrow) * 768 + h * 64;
#pragma unroll
  for (int c = 0; c < 4; ++c) {
    ushort4 u;
    u.x = f2bf(oacc[c][0] * inv);
    u.y = f2bf(oacc[c][1] * inv);
    u.z = f2bf(oacc[c][2] * inv);
    u.w = f2bf(oacc[c][3] * inv);
    *(ushort4*)(ctx + crow + c*16 + g*4) = u;
  }
#undef STAGE
#undef SWZ
#undef LOADBIAS
}

// ---------------- LDS-staged proj GEMM: ctx[8192,768] @ Wp[768,768]^T + b ------
__global__ __launch_bounds__(256) void gemm_proj(
    const unsigned short* __restrict__ X,
    const unsigned short* __restrict__ W,
    const float* __restrict__ bias,
    float* __restrict__ out)
{
  __shared__ unsigned short As[128*40];
  __shared__ unsigned short Bs[128*40];
  const int K = 768;
  int tid = threadIdx.x;
  int bm = blockIdx.x & 63;
  int bn = blockIdx.x >> 6;
  int wave = tid >> 6, lane = tid & 63;
  int lo = lane & 15, g = lane >> 4;
  int wr = (wave >> 1) * 64, wc = (wave & 1) * 64;
  int row0 = bm * 128, col0 = bn * 128;

  int sr = tid >> 1;
  int sc = (tid & 1) * 16;
  const unsigned short* gA = X + (size_t)(row0 + sr) * K + sc;
  const unsigned short* gB = W + (size_t)(col0 + sr) * K + sc;
  unsigned short* sA = &As[sr * 40 + sc];
  unsigned short* sB = &Bs[sr * 40 + sc];

  f32x4 acc[4][4] = {};
  for (int k0 = 0; k0 < K; k0 += 32) {
    bf16x8 a0 = *(const bf16x8*)(gA + k0);
    bf16x8 a1 = *(const bf16x8*)(gA + k0 + 8);
    bf16x8 b0 = *(const bf16x8*)(gB + k0);
    bf16x8 b1 = *(const bf16x8*)(gB + k0 + 8);
    __syncthreads();
    *(bf16x8*)(sA)     = a0;
    *(bf16x8*)(sA + 8) = a1;
    *(bf16x8*)(sB)     = b0;
    *(bf16x8*)(sB + 8) = b1;
    __syncthreads();
    bf16x8 af[4], bf[4];
#pragma unroll
    for (int i = 0; i < 4; ++i) af[i] = *(const bf16x8*)&As[(wr + i*16 + lo)*40 + g*8];
#pragma unroll
    for (int i = 0; i < 4; ++i) bf[i] = *(const bf16x8*)&Bs[(wc + i*16 + lo)*40 + g*8];
#pragma unroll
    for (int mi = 0; mi < 4; ++mi)
#pragma unroll
      for (int ni = 0; ni < 4; ++ni)
        acc[mi][ni] = MFMA32(af[mi], bf[ni], acc[mi][ni]);
  }
  int orow0 = row0 + wr, ocol0 = col0 + wc;
#pragma unroll
  for (int ni = 0; ni < 4; ++ni) {
    int col = ocol0 + ni*16 + lo;
    float bc = bias[col];
#pragma unroll
    for (int mi = 0; mi < 4; ++mi) {
#pragma unroll
      for (int r = 0; r < 4; ++r) {
        int row = orow0 + mi*16 + g*4 + r;
        out[(size_t)row * 768 + col] = acc[mi][ni][r] + bc;
      }
    }
  }
}

extern "C" void kernel_launch(void* const* d_in, const int* in_sizes, int n_in,
                              void* d_out, int out_size, void* d_ws, size_t ws_size,
                              hipStream_t stream) {
  const float* x            = (const float*)d_in[0];
  const float* rel_pos_bias = (const float*)d_in[1];
  const int* mask           = (const int*)d_in[2];
  const float* Wqkv         = (const float*)d_in[3];
  const float* bqkv         = (const float*)d_in[4];
  const float* Wproj        = (const float*)d_in[5];
  const float* bproj        = (const float*)d_in[6];

  float* out0 = (float*)d_out;                         // [8,1024,768]
  float* out1 = out0 + (size_t)8 * 1024 * 768;         // [8,12,1024,1024]

  char* ws = (char*)d_ws;
  unsigned short* xb  = (unsigned short*)(ws);            // dead after gemm_qkv -> Vt
  unsigned short* wqb = (unsigned short*)(ws + 12582912);
  unsigned short* wpb = (unsigned short*)(ws + 16121856);
  unsigned short* Qb  = (unsigned short*)(ws + 17301504);
  unsigned short* Kb  = (unsigned short*)(ws + 29884416);
  unsigned short* Vb  = (unsigned short*)(ws + 42467328);
  unsigned short* ctx = (unsigned short*)(ws + 55050240);
  unsigned short* Vtb = xb;
  unsigned long long* mbits = (unsigned long long*)(ws + 67633152); // 1 MB
  unsigned short* biasb = (unsigned short*)(ws + 68681728);         // 25.2 MB opt

  int big = ws_size >= (size_t)68681728 + 25165824;

  cvt_all<<<8448, 256, 0, stream>>>(x, Wqkv, Wproj, xb);
  if (big) cvt_bias<<<12288, 256, 0, stream>>>(rel_pos_bias, biasb);

  gemm_qkv<<<1152, 256, 0, stream>>>(xb, wqb, bqkv, Qb, Kb, Vb);

  mask_to_bits<<<2048, 256, 0, stream>>>(mask, mbits);

  vtrans<<<dim3(16, 96), 256, 0, stream>>>(Vb, Vtb);

  if (big)
    attn_kernel<1><<<dim3(8, 96), 512, 0, stream>>>(Qb, Kb, Vtb, (const void*)biasb,
                                                    (const unsigned*)mbits, out1, ctx);
  else
    attn_kernel<0><<<dim3(8, 96), 512, 0, stream>>>(Qb, Kb, Vtb, (const void*)rel_pos_bias,
                                                    (const unsigned*)mbits, out1, ctx);

  gemm_proj<<<384, 256, 0, stream>>>(ctx, wpb, bproj, out0);
}